// Round 13
// baseline (153.965 us; speedup 1.0000x reference)
//
#include <hip/hip_runtime.h>
#include <hip/hip_bf16.h>

// B=4, S=2048, E=512, H=8, D=64. out = attn(x@wq+bq, x@wk+bk, x@wv+bv),
// scores MULTIPLIED by 8 (reference divides by D^-0.5).
// Precision: split-bf16 (hi+lo) for Q/K projections and QK^T; bf16 V/PV.
// Round 12: intra-block split-K. r11 lesson: global split-S kills L2 reuse
// (FETCH 21->284 MB). r10 lesson: LDS read BW is the wall (~47us of 87us).
// Fix: keep r10 shell (8 waves, KBLK=64 dbuf, same staging/fetch pattern,
// 4 waves/SIMD) but waves = 4 q-groups x 2 k-halves: 32 q-rows x 32 k-rows
// per wave per tile -> LDS bytes/tile/wave 28KB/16q -> 16KB/32q (3.5x/q).
// Per-k-half online softmax; exact flash merge ONCE in LDS at the end.

#define SE 2048
#define EB 512
#define BB 4
#define HH 8
#define DD 64
#define BHN (BB*HH)

typedef __attribute__((ext_vector_type(8))) short short8;
typedef __attribute__((ext_vector_type(4))) float f32x4;

#define MFMA16(a, b, c) __builtin_amdgcn_mfma_f32_16x16x32_bf16((a), (b), (c), 0, 0, 0)

#if __has_builtin(__builtin_amdgcn_exp2f)
#define EXP2(x) __builtin_amdgcn_exp2f(x)
#else
#define EXP2(x) exp2f(x)
#endif

__device__ __forceinline__ unsigned short f2bf(float f) {
    union { float f; unsigned u; } x; x.f = f;
    unsigned r = x.u + 0x7fffu + ((x.u >> 16) & 1u);
    return (unsigned short)(r >> 16);
}
__device__ __forceinline__ float bf2f(unsigned short b) {
    union { unsigned u; float f; } x; x.u = ((unsigned)b) << 16;
    return x.f;
}
// native cast pack: compiler lowers pairs to v_cvt_pk_bf16_f32 (RNE)
__device__ __forceinline__ unsigned packbf2(float a, float b) {
    unsigned short lo = __bfloat16_as_ushort(__float2bfloat16(a));
    unsigned short hi = __bfloat16_as_ushort(__float2bfloat16(b));
    return (unsigned)lo | ((unsigned)hi << 16);
}

// ---- prep 1: split x (fp32) into hi/lo bf16, vectorized ----
__global__ void xsplit_kernel(const float* __restrict__ x,
                              unsigned short* __restrict__ xh,
                              unsigned short* __restrict__ xl, int n4) {
    int i = blockIdx.x * blockDim.x + threadIdx.x;
    if (i >= n4) return;
    float4 v = reinterpret_cast<const float4*>(x)[i];
    float f[4] = {v.x, v.y, v.z, v.w};
    ushort4 hv, lv;
    unsigned short hh[4], ll[4];
#pragma unroll
    for (int j = 0; j < 4; j++) {
        hh[j] = f2bf(f[j]);
        ll[j] = f2bf(f[j] - bf2f(hh[j]));
    }
    hv.x = hh[0]; hv.y = hh[1]; hv.z = hh[2]; hv.w = hh[3];
    lv.x = ll[0]; lv.y = ll[1]; lv.z = ll[2]; lv.w = ll[3];
    reinterpret_cast<ushort4*>(xh)[i] = hv;
    reinterpret_cast<ushort4*>(xl)[i] = lv;
}

// ---- prep 2: split + transpose weights into wt[hi/lo] layout [3*512 n][512 k] ----
__global__ void wsplit_kernel(const float* __restrict__ wq, const float* __restrict__ wk,
                              const float* __restrict__ wv,
                              unsigned short* __restrict__ wth,
                              unsigned short* __restrict__ wtl) {
    int tid = blockIdx.x * blockDim.x + threadIdx.x;
    if (tid >= 3 * 512 * 512) return;
    int n = tid & 511;
    int k = (tid >> 9) & 511;
    int m = tid >> 18;
    const float* w = (m == 0) ? wq : ((m == 1) ? wk : wv);
    float v = w[k * 512 + n];            // w is [k_in][n_out]
    unsigned short hb = f2bf(v);
    int o = ((m * 512 + n) << 9) + k;    // wt is [n][k]
    wth[o] = hb;
    wtl[o] = f2bf(v - bf2f(hb));
}

// stage 32 rows (4 KB) of a [128][64]-bf16 tile: linear LDS dest,
// inverse-swizzled global source.
__device__ __forceinline__ void stage4(const unsigned short* __restrict__ g,
                                       char* lbase, int wave, int srow, int scol,
                                       int kk) {
#pragma unroll
    for (int j = 0; j < 4; j++) {
        __builtin_amdgcn_global_load_lds(
            (const __attribute__((address_space(1))) void*)(g + (size_t)(srow + j * 8) * 512 + kk + scol),
            (__attribute__((address_space(3))) void*)(lbase + wave * 4096 + j * 1024),
            16, 0, 0);
    }
}

// ---- proj v3: tiled GEMM [8192,512]@[512,512] x3, LDS-staged, swizzled ----
template <int THREE>
__global__ __launch_bounds__(256) void proj_kernel(
    const unsigned short* __restrict__ xh, const unsigned short* __restrict__ xl,
    const unsigned short* __restrict__ wth, const unsigned short* __restrict__ wtl,
    const float* __restrict__ bq, const float* __restrict__ bk, const float* __restrict__ bv,
    unsigned short* __restrict__ qh, unsigned short* __restrict__ ql,
    unsigned short* __restrict__ kh, unsigned short* __restrict__ kl,
    unsigned short* __restrict__ vt) {
    constexpr int NTILE = THREE ? 4 : 2;
    __shared__ unsigned short lds[NTILE * 8192];   // tiles of [128][64] bf16
    char* LB = (char*)lds;
    constexpr int AHB = 0;
    constexpr int ALB = THREE ? 16384 : 0;
    constexpr int BHB = THREE ? 32768 : 16384;
    constexpr int BLB = THREE ? 49152 : 0;

    const int lane = threadIdx.x & 63;
    const int wave = threadIdx.x >> 6;
    const int lr = lane & 15, lk = lane >> 4;
    const int mat = THREE ? blockIdx.z : 2;        // 0=q 1=k 2=v
    const int m0 = blockIdx.x * 128;
    const int n0 = blockIdx.y * 128;
    const int wr = wave >> 1, wc = wave & 1;

    const unsigned short* Ah = xh + (size_t)m0 * 512;
    const unsigned short* Al = xl + (size_t)m0 * 512;
    const unsigned short* Bh = wth + (size_t)(mat * 512 + n0) * 512;
    const unsigned short* Bl = wtl + (size_t)(mat * 512 + n0) * 512;

    const int srow = wave * 32 + (lane >> 3);
    const int scol = 8 * ((lane & 7) ^ (lane >> 3));
    const int swzr = (lr & 7) << 4;

    f32x4 acc[4][4];
#pragma unroll
    for (int mi = 0; mi < 4; mi++)
#pragma unroll
        for (int ni = 0; ni < 4; ni++)
#pragma unroll
            for (int r = 0; r < 4; r++) acc[mi][ni][r] = 0.f;

    for (int t = 0; t < 8; t++) {
        const int kk = t * 64;
        stage4(Ah, LB + AHB, wave, srow, scol, kk);
        if (THREE) stage4(Al, LB + ALB, wave, srow, scol, kk);
        stage4(Bh, LB + BHB, wave, srow, scol, kk);
        if (THREE) stage4(Bl, LB + BLB, wave, srow, scol, kk);
        __syncthreads();

#pragma unroll
        for (int ks = 0; ks < 2; ks++) {
            short8 ah[4], al[4], bh8[4], bl8[4];
            const int cb = (ks * 64 + lk * 16) ^ swzr;
#pragma unroll
            for (int i = 0; i < 4; i++) {
                const int ao = (wr * 64 + i * 16 + lr) * 128 + cb;
                const int bo = (wc * 64 + i * 16 + lr) * 128 + cb;
                ah[i] = *reinterpret_cast<const short8*>(LB + AHB + ao);
                if (THREE) al[i] = *reinterpret_cast<const short8*>(LB + ALB + ao);
                bh8[i] = *reinterpret_cast<const short8*>(LB + BHB + bo);
                if (THREE) bl8[i] = *reinterpret_cast<const short8*>(LB + BLB + bo);
            }
#pragma unroll
            for (int mi = 0; mi < 4; mi++)
#pragma unroll
                for (int ni = 0; ni < 4; ni++) {
                    acc[mi][ni] = MFMA16(ah[mi], bh8[ni], acc[mi][ni]);
                    if (THREE) {
                        acc[mi][ni] = MFMA16(ah[mi], bl8[ni], acc[mi][ni]);
                        acc[mi][ni] = MFMA16(al[mi], bh8[ni], acc[mi][ni]);
                    }
                }
        }
        __syncthreads();
    }

    const float* bias = THREE ? ((mat == 0) ? bq : bk) : bv;
#pragma unroll
    for (int ni = 0; ni < 4; ni++) {
        const int col = n0 + wc * 64 + ni * 16 + lr;
        const float bsv = bias[col];
        const int h = col >> 6, d = col & 63;
#pragma unroll
        for (int mi = 0; mi < 4; mi++) {
#pragma unroll
            for (int r = 0; r < 4; r++) {
                const int row = m0 + wr * 64 + mi * 16 + lk * 4 + r;
                const int b_ = row >> 11, s = row & 2047;
                const int bh_ = b_ * HH + h;
                const float val = acc[mi][ni][r] + bsv;
                if (THREE) {
                    const unsigned short hb = f2bf(val);
                    const int o = (bh_ * SE + s) * DD + d;
                    if (mat == 0) { qh[o] = hb; ql[o] = f2bf(val - bf2f(hb)); }
                    else          { kh[o] = hb; kl[o] = f2bf(val - bf2f(hb)); }
                } else {
                    vt[(bh_ * DD + d) * SE + s] = f2bf(val);
                }
            }
        }
    }
}

// ---- attention v9: 8 waves = 4 q-groups x 2 k-halves, intra-block split-K ----
// Block covers 128 q-rows, all 32 k-tiles (staging pattern == round 10 ->
// same L2 behavior). Wave (qg,khf): 32 q-rows x rows [khf*32,khf*32+32) of
// each 64-row K tile. Per-wave LDS/tile: K 8KB + V 4KB + P 2+2KB = 16KB/32q.
// Per-k-half online softmax (m,l,o); exact flash merge in LDS at the end.
// LDS: 2x24KB dbuf + 8x2KB P = 64KB; merge area reuses dbuf space.
__global__ __launch_bounds__(512, 4) void attn_kernel(
    const unsigned short* __restrict__ qh, const unsigned short* __restrict__ ql,
    const unsigned short* __restrict__ kh, const unsigned short* __restrict__ kl,
    const unsigned short* __restrict__ vt, float* __restrict__ out) {
    __shared__ char LB[65536];
    const int lane = threadIdx.x & 63, wave = threadIdx.x >> 6;
    const int lr = lane & 15, lk = lane >> 4;
    const int qg = wave >> 1, khf = wave & 1;
    const int bh = blockIdx.x;               // 0..31
    const int b_ = bh >> 3, h = bh & 7;
    const int q0 = blockIdx.y * 128 + qg * 32;
    const int base = bh * SE * DD;
    const unsigned short* vbase = vt + bh * DD * SE;
    const float CL = 11.54156031f;           // 8 * log2(e)
    const int swz = (lr & 7) << 4;

    // ---- staging: 24 chunks of 1KB; wave handles c = wave*3 + i (as r10) ----
    const unsigned short* gp[3];
    int ginc[3], goff[3];
    {
        const int rIn = lane >> 3;
        const int c16 = (lane & 7) ^ rIn;          // inverse-swizzled col
#pragma unroll
        for (int i = 0; i < 3; i++) {
            const int c = wave * 3 + i;
            const int mat = c >> 3, grp = c & 7;
            const int row = grp * 8 + rIn;
            if (mat == 0)      { gp[i] = kh + base + row * DD + c16 * 8;  ginc[i] = 64 * DD; }
            else if (mat == 1) { gp[i] = kl + base + row * DD + c16 * 8;  ginc[i] = 64 * DD; }
            else               { gp[i] = vbase + row * SE + c16 * 8;      ginc[i] = 64; }
            goff[i] = mat * 8192 + grp * 1024;
        }
    }

    // Q fragments (B-operand), 2 subtiles of 16 q-rows
    short8 qhf[2][2], qlf[2][2];
#pragma unroll
    for (int qs = 0; qs < 2; qs++) {
        const int qoff = base + (q0 + qs * 16 + lr) * DD + lk * 8;
        qhf[qs][0] = *reinterpret_cast<const short8*>(qh + qoff);
        qhf[qs][1] = *reinterpret_cast<const short8*>(qh + qoff + 32);
        qlf[qs][0] = *reinterpret_cast<const short8*>(ql + qoff);
        qlf[qs][1] = *reinterpret_cast<const short8*>(ql + qoff + 32);
    }

    float m[2] = {-3.0e4f, -3.0e4f}, l[2] = {0.f, 0.f};
    f32x4 o[2][4];
#pragma unroll
    for (int qs = 0; qs < 2; qs++)
#pragma unroll
        for (int dnt = 0; dnt < 4; dnt++)
#pragma unroll
            for (int r = 0; r < 4; r++) o[qs][dnt][r] = 0.f;

    char* myp = LB + 49152 + wave * 2048;     // per-wave P tile, reused per qs

    // prologue: stage tile 0 into buffer 0
#pragma unroll
    for (int i = 0; i < 3; i++) {
        __builtin_amdgcn_global_load_lds(
            (const __attribute__((address_space(1))) void*)gp[i],
            (__attribute__((address_space(3))) void*)(LB + goff[i]), 16, 0, 0);
        gp[i] += ginc[i];
    }
    __syncthreads();   // implicit vmcnt(0): tile 0 staged

    for (int kt = 0; kt < 32; kt++) {
        const char* KB = LB + (kt & 1) * 24576;
        if (kt < 31) {
            const int nb = ((kt + 1) & 1) * 24576;
#pragma unroll
            for (int i = 0; i < 3; i++) {
                __builtin_amdgcn_global_load_lds(
                    (const __attribute__((address_space(1))) void*)gp[i],
                    (__attribute__((address_space(3))) void*)(LB + nb + goff[i]), 16, 0, 0);
                gp[i] += ginc[i];
            }
        }

        f32x4 s[2][2];
#pragma unroll
        for (int qs = 0; qs < 2; qs++)
#pragma unroll
            for (int knt = 0; knt < 2; knt++)
#pragma unroll
                for (int r = 0; r < 4; r++) s[qs][knt][r] = 0.f;

        // QK^T over this wave's k-half: rows khf*32 + knt*16 + lr
        __builtin_amdgcn_s_setprio(1);
#pragma unroll
        for (int knt = 0; knt < 2; knt++) {
            const int rb = (khf * 32 + knt * 16 + lr) * 128;
            short8 kh0 = *reinterpret_cast<const short8*>(KB + rb + ((lk * 16) ^ swz));
            short8 kh1 = *reinterpret_cast<const short8*>(KB + rb + ((64 + lk * 16) ^ swz));
            short8 kl0 = *reinterpret_cast<const short8*>(KB + 8192 + rb + ((lk * 16) ^ swz));
            short8 kl1 = *reinterpret_cast<const short8*>(KB + 8192 + rb + ((64 + lk * 16) ^ swz));
#pragma unroll
            for (int qs = 0; qs < 2; qs++) {
                s[qs][knt] = MFMA16(kh0, qhf[qs][0], s[qs][knt]);
                s[qs][knt] = MFMA16(kh1, qhf[qs][1], s[qs][knt]);
                s[qs][knt] = MFMA16(kl0, qhf[qs][0], s[qs][knt]);
                s[qs][knt] = MFMA16(kl1, qhf[qs][1], s[qs][knt]);
                s[qs][knt] = MFMA16(kh0, qlf[qs][0], s[qs][knt]);
                s[qs][knt] = MFMA16(kh1, qlf[qs][1], s[qs][knt]);
            }
        }
        __builtin_amdgcn_s_setprio(0);

        // V fragments: this wave's k-half columns (khf*32 elems = khf*64 bytes)
        short8 vf[4];
#pragma unroll
        for (int dnt = 0; dnt < 4; dnt++) {
            const int rv = (dnt * 16 + lr) * 128;
            vf[dnt] = *reinterpret_cast<const short8*>(KB + 16384 + rv + ((khf * 64 + lk * 16) ^ swz));
        }

        // per-subtile: softmax over 32 k -> P -> PV (1 MFMA/dnt, k=32)
#pragma unroll
        for (int qs = 0; qs < 2; qs++) {
            float mt = fmaxf(fmaxf(s[qs][0][0], s[qs][0][1]), fmaxf(s[qs][0][2], s[qs][0][3]));
#pragma unroll
            for (int r = 0; r < 4; r++) mt = fmaxf(mt, s[qs][1][r]);
            mt = fmaxf(mt, __shfl_xor(mt, 16));
            mt = fmaxf(mt, __shfl_xor(mt, 32));

            if (!__all(mt <= m[qs] + 0.69314718f)) {   // defer-max
                const float mn = fmaxf(m[qs], mt);
                const float fac = EXP2((m[qs] - mn) * CL);
                l[qs] *= fac;
#pragma unroll
                for (int dnt = 0; dnt < 4; dnt++)
#pragma unroll
                    for (int r = 0; r < 4; r++) o[qs][dnt][r] *= fac;
                m[qs] = mn;
            }
            const float nm = -m[qs] * CL;
            float rs = 0.f;
#pragma unroll
            for (int knt = 0; knt < 2; knt++) {
                float p0 = EXP2(fmaf(s[qs][knt][0], CL, nm));
                float p1 = EXP2(fmaf(s[qs][knt][1], CL, nm));
                float p2 = EXP2(fmaf(s[qs][knt][2], CL, nm));
                float p3 = EXP2(fmaf(s[qs][knt][3], CL, nm));
                rs += (p0 + p1) + (p2 + p3);
                unsigned w0 = packbf2(p0, p1);
                unsigned w1 = packbf2(p2, p3);
                const int cb = (knt * 32 + lk * 8) ^ swz;
                *reinterpret_cast<uint2*>(myp + lr * 128 + cb) = make_uint2(w0, w1);
            }
            rs += __shfl_xor(rs, 16);
            rs += __shfl_xor(rs, 32);
            l[qs] += rs;

            short8 pa = *reinterpret_cast<const short8*>(myp + lr * 128 + ((lk * 16) ^ swz));
            __builtin_amdgcn_s_setprio(1);
#pragma unroll
            for (int dnt = 0; dnt < 4; dnt++)
                o[qs][dnt] = MFMA16(vf[dnt], pa, o[qs][dnt]);
            __builtin_amdgcn_s_setprio(0);
        }

        __syncthreads();   // drains vmcnt (next tile staged) + LDS reads done
    }

    // ---- block-local flash merge of the two k-halves (exact, fp32) ----
    // khf=1 waves publish (o, m, l) to LDS (dbuf region is free now).
    float* exo = (float*)(LB) + qg * 2048;            // [32 q][64 d] fp32
    float2* exm = (float2*)(LB + 32768) + qg * 32;    // [32 q] (m,l)
    if (khf == 1) {
#pragma unroll
        for (int qs = 0; qs < 2; qs++) {
            float* op = exo + (qs * 16 + lr) * 64 + lk * 4;
#pragma unroll
            for (int dnt = 0; dnt < 4; dnt++) {
                float4 val;
                val.x = o[qs][dnt][0]; val.y = o[qs][dnt][1];
                val.z = o[qs][dnt][2]; val.w = o[qs][dnt][3];
                *reinterpret_cast<float4*>(op + dnt * 16) = val;
            }
            if (lk == 0) exm[qs * 16 + lr] = make_float2(m[qs], l[qs]);
        }
    }
    __syncthreads();
    if (khf == 0) {
#pragma unroll
        for (int qs = 0; qs < 2; qs++) {
            const float2 ml1 = exm[qs * 16 + lr];
            const float M = fmaxf(m[qs], ml1.x);
            const float f0 = EXP2((m[qs] - M) * CL);
            const float f1 = EXP2((ml1.x - M) * CL);
            const float rl = 1.0f / (f0 * l[qs] + f1 * ml1.y);
            const float* ip = exo + (qs * 16 + lr) * 64 + lk * 4;
            float* op = out + (size_t)(b_ * SE + q0 + qs * 16 + lr) * EB + h * DD + lk * 4;
#pragma unroll
            for (int dnt = 0; dnt < 4; dnt++) {
                float4 o1 = *reinterpret_cast<const float4*>(ip + dnt * 16);
                float4 val;
                val.x = (f0 * o[qs][dnt][0] + f1 * o1.x) * rl;
                val.y = (f0 * o[qs][dnt][1] + f1 * o1.y) * rl;
                val.z = (f0 * o[qs][dnt][2] + f1 * o1.z) * rl;
                val.w = (f0 * o[qs][dnt][3] + f1 * o1.w) * rl;
                *reinterpret_cast<float4*>(op + dnt * 16) = val;
            }
        }
    }
}

extern "C" void kernel_launch(void* const* d_in, const int* in_sizes, int n_in,
                              void* d_out, int out_size, void* d_ws, size_t ws_size,
                              hipStream_t stream) {
    const float* x  = (const float*)d_in[0];
    const float* wq = (const float*)d_in[1];
    const float* bq = (const float*)d_in[2];
    const float* wk = (const float*)d_in[3];
    const float* bk = (const float*)d_in[4];
    const float* wv = (const float*)d_in[5];
    const float* bv = (const float*)d_in[6];
    float* out = (float*)d_out;

    unsigned short* ws = (unsigned short*)d_ws;
    const int NX = 8192 * 512;
    const int NW = 3 * 512 * 512;
    const int NQ = BHN * SE * DD;
    unsigned short* xh  = ws;
    unsigned short* xl  = xh + NX;
    unsigned short* wth = xl + NX;
    unsigned short* wtl = wth + NW;
    unsigned short* qhp = wtl + NW;
    unsigned short* qlp = qhp + NQ;
    unsigned short* khp = qlp + NQ;
    unsigned short* klp = khp + NQ;
    unsigned short* vtp = klp + NQ;

    xsplit_kernel<<<NX / 4 / 256, 256, 0, stream>>>(x, xh, xl, NX / 4);
    wsplit_kernel<<<NW / 256, 256, 0, stream>>>(wq, wk, wv, wth, wtl);
    proj_kernel<1><<<dim3(64, 4, 2), 256, 0, stream>>>(xh, xl, wth, wtl, bq, bk, bv,
                                                       qhp, qlp, khp, klp, vtp);
    proj_kernel<0><<<dim3(64, 4), 256, 0, stream>>>(xh, xl, wth, wtl, bq, bk, bv,
                                                    qhp, qlp, khp, klp, vtp);
    attn_kernel<<<dim3(32, 16), 512, 0, stream>>>(qhp, qlp, khp, klp, vtp, out);
}

// Round 14
// 150.683 us; speedup vs baseline: 1.0218x; 1.0218x over previous
//
#include <hip/hip_runtime.h>
#include <hip/hip_bf16.h>

// B=4, S=2048, E=512, H=8, D=64. out = attn(x@wq+bq, x@wk+bk, x@wv+bv),
// scores MULTIPLIED by 8 (reference divides by D^-0.5).
// Precision: split-bf16 (hi+lo) for Q/K projections and QK^T; bf16 V/PV.
// Round 14: attn on 32x32x16 MFMA, 32 q-rows/wave, P fully in-register
// (swapped QK^T 32x32 C-layout -> cvt_pk + shfl_xor(32) redistribution,
// no P LDS buffer, no LDS round-trip). r10 staging shell kept (KBLK=64,
// dbuf, 24x1KB chunks, both-sides swizzle). 4 waves/block, grid (32,16).

#define SE 2048
#define EB 512
#define BB 4
#define HH 8
#define DD 64
#define BHN (BB*HH)

typedef __attribute__((ext_vector_type(8))) short short8;
typedef __attribute__((ext_vector_type(4))) float f32x4;
typedef __attribute__((ext_vector_type(16))) float f32x16;

#define MFMA16(a, b, c) __builtin_amdgcn_mfma_f32_16x16x32_bf16((a), (b), (c), 0, 0, 0)
#define MFMA32(a, b, c) __builtin_amdgcn_mfma_f32_32x32x16_bf16((a), (b), (c), 0, 0, 0)

#if __has_builtin(__builtin_amdgcn_exp2f)
#define EXP2(x) __builtin_amdgcn_exp2f(x)
#else
#define EXP2(x) exp2f(x)
#endif

__device__ __forceinline__ unsigned short f2bf(float f) {
    union { float f; unsigned u; } x; x.f = f;
    unsigned r = x.u + 0x7fffu + ((x.u >> 16) & 1u);
    return (unsigned short)(r >> 16);
}
__device__ __forceinline__ float bf2f(unsigned short b) {
    union { unsigned u; float f; } x; x.u = ((unsigned)b) << 16;
    return x.f;
}
// native cast pack: compiler lowers pairs to v_cvt_pk_bf16_f32 (RNE)
__device__ __forceinline__ unsigned packbf2(float a, float b) {
    unsigned short lo = __bfloat16_as_ushort(__float2bfloat16(a));
    unsigned short hi = __bfloat16_as_ushort(__float2bfloat16(b));
    return (unsigned)lo | ((unsigned)hi << 16);
}

// ---- prep 1: split x (fp32) into hi/lo bf16, vectorized ----
__global__ void xsplit_kernel(const float* __restrict__ x,
                              unsigned short* __restrict__ xh,
                              unsigned short* __restrict__ xl, int n4) {
    int i = blockIdx.x * blockDim.x + threadIdx.x;
    if (i >= n4) return;
    float4 v = reinterpret_cast<const float4*>(x)[i];
    float f[4] = {v.x, v.y, v.z, v.w};
    ushort4 hv, lv;
    unsigned short hh[4], ll[4];
#pragma unroll
    for (int j = 0; j < 4; j++) {
        hh[j] = f2bf(f[j]);
        ll[j] = f2bf(f[j] - bf2f(hh[j]));
    }
    hv.x = hh[0]; hv.y = hh[1]; hv.z = hh[2]; hv.w = hh[3];
    lv.x = ll[0]; lv.y = ll[1]; lv.z = ll[2]; lv.w = ll[3];
    reinterpret_cast<ushort4*>(xh)[i] = hv;
    reinterpret_cast<ushort4*>(xl)[i] = lv;
}

// ---- prep 2: split + transpose weights into wt[hi/lo] layout [3*512 n][512 k] ----
__global__ void wsplit_kernel(const float* __restrict__ wq, const float* __restrict__ wk,
                              const float* __restrict__ wv,
                              unsigned short* __restrict__ wth,
                              unsigned short* __restrict__ wtl) {
    int tid = blockIdx.x * blockDim.x + threadIdx.x;
    if (tid >= 3 * 512 * 512) return;
    int n = tid & 511;
    int k = (tid >> 9) & 511;
    int m = tid >> 18;
    const float* w = (m == 0) ? wq : ((m == 1) ? wk : wv);
    float v = w[k * 512 + n];            // w is [k_in][n_out]
    unsigned short hb = f2bf(v);
    int o = ((m * 512 + n) << 9) + k;    // wt is [n][k]
    wth[o] = hb;
    wtl[o] = f2bf(v - bf2f(hb));
}

// stage 32 rows (4 KB) of a [128][64]-bf16 tile: linear LDS dest,
// inverse-swizzled global source.
__device__ __forceinline__ void stage4(const unsigned short* __restrict__ g,
                                       char* lbase, int wave, int srow, int scol,
                                       int kk) {
#pragma unroll
    for (int j = 0; j < 4; j++) {
        __builtin_amdgcn_global_load_lds(
            (const __attribute__((address_space(1))) void*)(g + (size_t)(srow + j * 8) * 512 + kk + scol),
            (__attribute__((address_space(3))) void*)(lbase + wave * 4096 + j * 1024),
            16, 0, 0);
    }
}

// ---- proj v3: tiled GEMM [8192,512]@[512,512] x3, LDS-staged, swizzled ----
template <int THREE>
__global__ __launch_bounds__(256) void proj_kernel(
    const unsigned short* __restrict__ xh, const unsigned short* __restrict__ xl,
    const unsigned short* __restrict__ wth, const unsigned short* __restrict__ wtl,
    const float* __restrict__ bq, const float* __restrict__ bk, const float* __restrict__ bv,
    unsigned short* __restrict__ qh, unsigned short* __restrict__ ql,
    unsigned short* __restrict__ kh, unsigned short* __restrict__ kl,
    unsigned short* __restrict__ vt) {
    constexpr int NTILE = THREE ? 4 : 2;
    __shared__ unsigned short lds[NTILE * 8192];   // tiles of [128][64] bf16
    char* LB = (char*)lds;
    constexpr int AHB = 0;
    constexpr int ALB = THREE ? 16384 : 0;
    constexpr int BHB = THREE ? 32768 : 16384;
    constexpr int BLB = THREE ? 49152 : 0;

    const int lane = threadIdx.x & 63;
    const int wave = threadIdx.x >> 6;
    const int lr = lane & 15, lk = lane >> 4;
    const int mat = THREE ? blockIdx.z : 2;        // 0=q 1=k 2=v
    const int m0 = blockIdx.x * 128;
    const int n0 = blockIdx.y * 128;
    const int wr = wave >> 1, wc = wave & 1;

    const unsigned short* Ah = xh + (size_t)m0 * 512;
    const unsigned short* Al = xl + (size_t)m0 * 512;
    const unsigned short* Bh = wth + (size_t)(mat * 512 + n0) * 512;
    const unsigned short* Bl = wtl + (size_t)(mat * 512 + n0) * 512;

    const int srow = wave * 32 + (lane >> 3);
    const int scol = 8 * ((lane & 7) ^ (lane >> 3));
    const int swzr = (lr & 7) << 4;

    f32x4 acc[4][4];
#pragma unroll
    for (int mi = 0; mi < 4; mi++)
#pragma unroll
        for (int ni = 0; ni < 4; ni++)
#pragma unroll
            for (int r = 0; r < 4; r++) acc[mi][ni][r] = 0.f;

    for (int t = 0; t < 8; t++) {
        const int kk = t * 64;
        stage4(Ah, LB + AHB, wave, srow, scol, kk);
        if (THREE) stage4(Al, LB + ALB, wave, srow, scol, kk);
        stage4(Bh, LB + BHB, wave, srow, scol, kk);
        if (THREE) stage4(Bl, LB + BLB, wave, srow, scol, kk);
        __syncthreads();

#pragma unroll
        for (int ks = 0; ks < 2; ks++) {
            short8 ah[4], al[4], bh8[4], bl8[4];
            const int cb = (ks * 64 + lk * 16) ^ swzr;
#pragma unroll
            for (int i = 0; i < 4; i++) {
                const int ao = (wr * 64 + i * 16 + lr) * 128 + cb;
                const int bo = (wc * 64 + i * 16 + lr) * 128 + cb;
                ah[i] = *reinterpret_cast<const short8*>(LB + AHB + ao);
                if (THREE) al[i] = *reinterpret_cast<const short8*>(LB + ALB + ao);
                bh8[i] = *reinterpret_cast<const short8*>(LB + BHB + bo);
                if (THREE) bl8[i] = *reinterpret_cast<const short8*>(LB + BLB + bo);
            }
#pragma unroll
            for (int mi = 0; mi < 4; mi++)
#pragma unroll
                for (int ni = 0; ni < 4; ni++) {
                    acc[mi][ni] = MFMA16(ah[mi], bh8[ni], acc[mi][ni]);
                    if (THREE) {
                        acc[mi][ni] = MFMA16(ah[mi], bl8[ni], acc[mi][ni]);
                        acc[mi][ni] = MFMA16(al[mi], bh8[ni], acc[mi][ni]);
                    }
                }
        }
        __syncthreads();
    }

    const float* bias = THREE ? ((mat == 0) ? bq : bk) : bv;
#pragma unroll
    for (int ni = 0; ni < 4; ni++) {
        const int col = n0 + wc * 64 + ni * 16 + lr;
        const float bsv = bias[col];
        const int h = col >> 6, d = col & 63;
#pragma unroll
        for (int mi = 0; mi < 4; mi++) {
#pragma unroll
            for (int r = 0; r < 4; r++) {
                const int row = m0 + wr * 64 + mi * 16 + lk * 4 + r;
                const int b_ = row >> 11, s = row & 2047;
                const int bh_ = b_ * HH + h;
                const float val = acc[mi][ni][r] + bsv;
                if (THREE) {
                    const unsigned short hb = f2bf(val);
                    const int o = (bh_ * SE + s) * DD + d;
                    if (mat == 0) { qh[o] = hb; ql[o] = f2bf(val - bf2f(hb)); }
                    else          { kh[o] = hb; kl[o] = f2bf(val - bf2f(hb)); }
                } else {
                    vt[(bh_ * DD + d) * SE + s] = f2bf(val);
                }
            }
        }
    }
}

// ---- attention v10: 32x32x16 MFMA, 32 q/wave, in-register P, KBLK=64 dbuf ----
// Swapped QK^T: C[k][q] with q = lane&31 (one q-row per lane pair), k spread
// over regs: k_local = (reg&3) + 8*(reg>>2) + 4*hi, hi = lane>>5.
// PV B-frag (k = 8*hi + e) built in-register: cvt_pk pairs + shfl_xor(32).
// LDS: 2 x 24KB K/V dbuf only (no P buffer). 4 waves/block, grid (32,16).
__global__ __launch_bounds__(256, 2) void attn_kernel(
    const unsigned short* __restrict__ qh, const unsigned short* __restrict__ ql,
    const unsigned short* __restrict__ kh, const unsigned short* __restrict__ kl,
    const unsigned short* __restrict__ vt, float* __restrict__ out) {
    __shared__ char LB[49152];
    const int lane = threadIdx.x & 63, wave = threadIdx.x >> 6;
    const int q31 = lane & 31, hi = lane >> 5;
    const int bh = blockIdx.x;               // 0..31
    const int b_ = bh >> 3, h = bh & 7;
    const int q0 = blockIdx.y * 128 + wave * 32;
    const int base = bh * SE * DD;
    const unsigned short* vbase = vt + bh * DD * SE;
    const float CL = 11.54156031f;           // 8 * log2(e)
    const int swz = (lane & 7) << 4;         // read-side row swizzle ((r&7)<<4)

    // ---- staging: 24 chunks of 1KB; wave handles c = wave*6 + i ----
    const unsigned short* gp[6];
    int ginc[6], goff[6];
    {
        const int rIn = lane >> 3;
        const int c16 = (lane & 7) ^ rIn;          // inverse-swizzled col
#pragma unroll
        for (int i = 0; i < 6; i++) {
            const int c = wave * 6 + i;
            const int mat = c >> 3, grp = c & 7;
            const int row = grp * 8 + rIn;
            if (mat == 0)      { gp[i] = kh + base + row * DD + c16 * 8;  ginc[i] = 64 * DD; }
            else if (mat == 1) { gp[i] = kl + base + row * DD + c16 * 8;  ginc[i] = 64 * DD; }
            else               { gp[i] = vbase + row * SE + c16 * 8;      ginc[i] = 64; }
            goff[i] = mat * 8192 + grp * 1024;
        }
    }

    // Q fragments (B-operand of 32x32x16): col = q31, k = 8*hi + e, 4 d-steps
    short8 qhf[4], qlf[4];
    {
        const unsigned short* qb  = qh + base + (q0 + q31) * DD + 8 * hi;
        const unsigned short* qlb = ql + base + (q0 + q31) * DD + 8 * hi;
#pragma unroll
        for (int ds = 0; ds < 4; ds++) {
            qhf[ds] = *reinterpret_cast<const short8*>(qb + ds * 16);
            qlf[ds] = *reinterpret_cast<const short8*>(qlb + ds * 16);
        }
    }

    float m = -3.0e4f, l = 0.f;
    f32x16 o[2];
#pragma unroll
    for (int dt = 0; dt < 2; dt++)
#pragma unroll
        for (int r = 0; r < 16; r++) o[dt][r] = 0.f;

    // prologue: stage tile 0 into buffer 0
#pragma unroll
    for (int i = 0; i < 6; i++) {
        __builtin_amdgcn_global_load_lds(
            (const __attribute__((address_space(1))) void*)gp[i],
            (__attribute__((address_space(3))) void*)(LB + goff[i]), 16, 0, 0);
        gp[i] += ginc[i];
    }
    __syncthreads();   // implicit vmcnt(0): tile 0 staged

    for (int kt = 0; kt < 32; kt++) {
        const char* KB = LB + (kt & 1) * 24576;
        if (kt < 31) {
            const int nb = ((kt + 1) & 1) * 24576;
#pragma unroll
            for (int i = 0; i < 6; i++) {
                __builtin_amdgcn_global_load_lds(
                    (const __attribute__((address_space(1))) void*)gp[i],
                    (__attribute__((address_space(3))) void*)(LB + nb + goff[i]), 16, 0, 0);
                gp[i] += ginc[i];
            }
        }

        // QK^T: A = K rows (32x32x16), 2 k-subtiles x 4 d-steps x 3 terms
        f32x16 s[2];
#pragma unroll
        for (int kt2 = 0; kt2 < 2; kt2++)
#pragma unroll
            for (int r = 0; r < 16; r++) s[kt2][r] = 0.f;

        __builtin_amdgcn_s_setprio(1);
#pragma unroll
        for (int kt2 = 0; kt2 < 2; kt2++) {
            const int rb = (kt2 * 32 + q31) * 128;
#pragma unroll
            for (int ds = 0; ds < 4; ds++) {
                const int cb = (ds * 32 + 16 * hi) ^ swz;
                short8 khf = *reinterpret_cast<const short8*>(KB + rb + cb);
                short8 klf = *reinterpret_cast<const short8*>(KB + 8192 + rb + cb);
                s[kt2] = MFMA32(khf, qhf[ds], s[kt2]);
                s[kt2] = MFMA32(khf, qlf[ds], s[kt2]);
                s[kt2] = MFMA32(klf, qhf[ds], s[kt2]);
            }
        }
        __builtin_amdgcn_s_setprio(0);

        // V fragments (A-operand of PV): row = dt*32 + q31 (d), k = 8*hi+e
        short8 vf[2][2][2];
#pragma unroll
        for (int dt = 0; dt < 2; dt++) {
            const int rv = (dt * 32 + q31) * 128;
#pragma unroll
            for (int kt2 = 0; kt2 < 2; kt2++)
#pragma unroll
                for (int f = 0; f < 2; f++)
                    vf[dt][kt2][f] = *reinterpret_cast<const short8*>(
                        KB + 16384 + rv + ((kt2 * 64 + f * 32 + 16 * hi) ^ swz));
        }

        // softmax (exp2 domain); lane owns q = q0+q31 (half the k per lane)
        float mt = s[0][0];
#pragma unroll
        for (int kt2 = 0; kt2 < 2; kt2++)
#pragma unroll
            for (int r = 0; r < 16; r++) mt = fmaxf(mt, s[kt2][r]);
        mt = fmaxf(mt, __shfl_xor(mt, 32));

        if (!__all(mt <= m + 0.69314718f)) {   // defer-max (P bounded by 2^8)
            const float mn = fmaxf(m, mt);
            const float fac = EXP2((m - mn) * CL);
            l *= fac;
#pragma unroll
            for (int dt = 0; dt < 2; dt++)
#pragma unroll
                for (int r = 0; r < 16; r++) o[dt][r] *= fac;
            m = mn;
        }
        const float nm = -m * CL;
        float rs = 0.f;

#pragma unroll
        for (int kt2 = 0; kt2 < 2; kt2++) {
            float p[16];
#pragma unroll
            for (int r = 0; r < 16; r++) {
                p[r] = EXP2(fmaf(s[kt2][r], CL, nm));
                rs += p[r];
            }
            unsigned w[8];
#pragma unroll
            for (int j = 0; j < 8; j++) w[j] = packbf2(p[2 * j], p[2 * j + 1]);

            // PV B-frags: k = f*16 + 8*hi + e; cross-half via shfl_xor(32)
#pragma unroll
            for (int f = 0; f < 2; f++) {
                unsigned x0 = hi ? w[4 * f] : w[4 * f + 2];
                unsigned x1 = hi ? w[4 * f + 1] : w[4 * f + 3];
                unsigned y0 = __shfl_xor(x0, 32);
                unsigned y1 = __shfl_xor(x1, 32);
                union { unsigned u[4]; short8 s8; } pu;
                pu.u[0] = hi ? y0 : w[4 * f];
                pu.u[1] = hi ? y1 : w[4 * f + 1];
                pu.u[2] = hi ? w[4 * f + 2] : y0;
                pu.u[3] = hi ? w[4 * f + 3] : y1;
                __builtin_amdgcn_s_setprio(1);
                o[0] = MFMA32(vf[0][kt2][f], pu.s8, o[0]);
                o[1] = MFMA32(vf[1][kt2][f], pu.s8, o[1]);
                __builtin_amdgcn_s_setprio(0);
            }
        }
        rs += __shfl_xor(rs, 32);
        l += rs;

        __syncthreads();   // drains vmcnt (next tile staged) + LDS reads done
    }

    // epilogue: o C-layout: col=q (q31), row d = (r&3)+8*(r>>2)+4*hi+32*dt
    const float rl = 1.0f / l;
    float* op = out + (size_t)(b_ * SE + q0 + q31) * EB + h * DD + 4 * hi;
#pragma unroll
    for (int dt = 0; dt < 2; dt++) {
#pragma unroll
        for (int a = 0; a < 4; a++) {
            float4 val;
            val.x = o[dt][4 * a + 0] * rl;
            val.y = o[dt][4 * a + 1] * rl;
            val.z = o[dt][4 * a + 2] * rl;
            val.w = o[dt][4 * a + 3] * rl;
            *reinterpret_cast<float4*>(op + dt * 32 + a * 8) = val;
        }
    }
}

extern "C" void kernel_launch(void* const* d_in, const int* in_sizes, int n_in,
                              void* d_out, int out_size, void* d_ws, size_t ws_size,
                              hipStream_t stream) {
    const float* x  = (const float*)d_in[0];
    const float* wq = (const float*)d_in[1];
    const float* bq = (const float*)d_in[2];
    const float* wk = (const float*)d_in[3];
    const float* bk = (const float*)d_in[4];
    const float* wv = (const float*)d_in[5];
    const float* bv = (const float*)d_in[6];
    float* out = (float*)d_out;

    unsigned short* ws = (unsigned short*)d_ws;
    const int NX = 8192 * 512;
    const int NW = 3 * 512 * 512;
    const int NQ = BHN * SE * DD;
    unsigned short* xh  = ws;
    unsigned short* xl  = xh + NX;
    unsigned short* wth = xl + NX;
    unsigned short* wtl = wth + NW;
    unsigned short* qhp = wtl + NW;
    unsigned short* qlp = qhp + NQ;
    unsigned short* khp = qlp + NQ;
    unsigned short* klp = khp + NQ;
    unsigned short* vtp = klp + NQ;

    xsplit_kernel<<<NX / 4 / 256, 256, 0, stream>>>(x, xh, xl, NX / 4);
    wsplit_kernel<<<NW / 256, 256, 0, stream>>>(wq, wk, wv, wth, wtl);
    proj_kernel<1><<<dim3(64, 4, 2), 256, 0, stream>>>(xh, xl, wth, wtl, bq, bk, bv,
                                                       qhp, qlp, khp, klp, vtp);
    proj_kernel<0><<<dim3(64, 4), 256, 0, stream>>>(xh, xl, wth, wtl, bq, bk, bv,
                                                    qhp, qlp, khp, klp, vtp);
    attn_kernel<<<dim3(32, 16), 256, 0, stream>>>(qhp, qlp, khp, klp, vtp, out);
}